// Round 6
// baseline (74.639 us; speedup 1.0000x reference)
//
#include <hip/hip_runtime.h>
#include <hip/hip_bf16.h>

// Linear attention (ELU feature map) via bf16 MFMA with hi/lo split-precision
// (fp32-accurate: x = hi(bf16) + lo(bf16), products via 3 MFMAs, lo*lo dropped).
//   K1: partial KV[d][m] + ksum[d] (ksum via MFMA vs all-ones B), NSPL=4,
//       2-deep register prefetch + LDS double-buffer, ONE barrier per tile.
//   K2: sum partials -> O = phiQ*KV, Z via MFMA, all operands hi/lo split.
// Fallback (ws too small): fp32 fused kernel (R1, verified).

constexpr int Bc = 4, Nc = 8, Hc = 8;
constexpr int Lc = 1024, Sc = 1024, Dc = 64, Mc = 64;
constexpr int HD = Hc * Dc;            // 512 floats between consecutive rows
constexpr int GROUPS = Bc * Nc * Hc;   // 256
constexpr int LSPLITS = 4;
constexpr int LROWS = Lc / LSPLITS;    // 256
constexpr int PARTIAL = Dc * Mc + Dc;  // 4160 floats per partial
constexpr int NTL = LROWS / 64;        // 4 l-tiles
constexpr int PADS = 36;               // K1 inner dim: 32 s + 4 pad (bf16)
constexpr int PADD = 68;               // K2 inner dim: 64 d + 4 pad (bf16)
constexpr float EPSF = 1e-6f;

typedef __attribute__((ext_vector_type(8))) __bf16 bf16x8;
typedef __attribute__((ext_vector_type(4))) float f32x4;

__device__ __forceinline__ float elup1(float x) {
    return x > 0.0f ? x + 1.0f : __expf(x);
}
__device__ __forceinline__ unsigned short f2bf(float f) {
    unsigned u = __builtin_bit_cast(unsigned, f);
    u += 0x7fffu + ((u >> 16) & 1u);          // round-to-nearest-even
    return (unsigned short)(u >> 16);
}
__device__ __forceinline__ float bf2f(unsigned short h) {
    return __builtin_bit_cast(float, (unsigned)h << 16);
}
// split x into hi+lo bf16 (lo = rounding residue, |lo| <= 2^-9 |x|)
__device__ __forceinline__ void splitbf(float x, unsigned short& h, unsigned short& l) {
    h = f2bf(x);
    l = f2bf(x - bf2f(h));
}
__device__ __forceinline__ unsigned pack2(unsigned short lo, unsigned short hi) {
    return (unsigned)lo | ((unsigned)hi << 16);
}
__device__ __forceinline__ bf16x8 ones_frag() {
    union { bf16x8 v; unsigned short s[8]; } u;
    #pragma unroll
    for (int i = 0; i < 8; ++i) u.s[i] = 0x3F80;   // bf16 1.0
    return u.v;
}

// ---------------- Kernel 1: partial KV via split-bf16 MFMA ----------------
template<int NSPL>
__global__ void __launch_bounds__(256, 4)
la_kv_mfma(const float* __restrict__ Kg, const float* __restrict__ Vg,
           const float* __restrict__ Mg, float* __restrict__ ws)
{
    constexpr int SR = Sc / NSPL;      // s-rows per block (256)
    constexpr int NT = SR / 32;        // tiles (8)

    __shared__ unsigned short kth[2][Dc][PADS];   // phiK hi
    __shared__ unsigned short ktl[2][Dc][PADS];   // phiK lo
    __shared__ unsigned short vth[2][Dc][PADS];   // V hi
    __shared__ unsigned short vtl[2][Dc][PADS];   // V lo   (total 36 KB)

    const int t    = threadIdx.x;
    const int tx   = t & 15;
    const int tyq  = t >> 4;       // 0..15
    const int lane = t & 63;
    const int w    = t >> 6;       // wave 0..3
    const int g    = blockIdx.y;
    const int sp   = blockIdx.x;
    const int h    = g & 7;
    const int bn   = g >> 3;
    const int b    = g >> 6;

    const size_t rowbase = (size_t)bn * Sc * HD + (size_t)h * Dc;
    const size_t mbase   = (size_t)b * Sc;
    const int    sbase   = sp * SR;

    // two named register sets (compile-time indexed -> no scratch)
    float4 kA0, kA1, vA0, vA1; float2 mA;
    float4 kB0, kB1, vB0, vB1; float2 mB;

    auto loadA_A = [&](int it) {
        const int s0 = sbase + it * 32 + 2 * tyq;
        const size_t off = rowbase + (size_t)s0 * HD + 4 * tx;
        kA0 = *reinterpret_cast<const float4*>(Kg + off);
        kA1 = *reinterpret_cast<const float4*>(Kg + off + HD);
        vA0 = *reinterpret_cast<const float4*>(Vg + off);
        vA1 = *reinterpret_cast<const float4*>(Vg + off + HD);
        mA  = *reinterpret_cast<const float2*>(Mg + mbase + s0);
    };
    auto loadA_B = [&](int it) {
        const int s0 = sbase + it * 32 + 2 * tyq;
        const size_t off = rowbase + (size_t)s0 * HD + 4 * tx;
        kB0 = *reinterpret_cast<const float4*>(Kg + off);
        kB1 = *reinterpret_cast<const float4*>(Kg + off + HD);
        vB0 = *reinterpret_cast<const float4*>(Vg + off);
        vB1 = *reinterpret_cast<const float4*>(Vg + off + HD);
        mB  = *reinterpret_cast<const float2*>(Mg + mbase + s0);
    };
    auto stage = [&](int buf, const float4& K0, const float4& K1,
                     const float4& V0, const float4& V1, const float2& M2) {
        const float k0[4] = {K0.x, K0.y, K0.z, K0.w};
        const float k1[4] = {K1.x, K1.y, K1.z, K1.w};
        const float v0[4] = {V0.x, V0.y, V0.z, V0.w};
        const float v1[4] = {V1.x, V1.y, V1.z, V1.w};
        #pragma unroll
        for (int i = 0; i < 4; ++i) {
            const float a0 = elup1(k0[i]) * M2.x;
            const float a1 = elup1(k1[i]) * M2.y;
            unsigned short h0, l0, h1, l1;
            splitbf(a0, h0, l0);
            splitbf(a1, h1, l1);
            *reinterpret_cast<unsigned*>(&kth[buf][4 * tx + i][2 * tyq]) = pack2(h0, h1);
            *reinterpret_cast<unsigned*>(&ktl[buf][4 * tx + i][2 * tyq]) = pack2(l0, l1);
            unsigned short vh0, vl0, vh1, vl1;
            splitbf(v0[i], vh0, vl0);
            splitbf(v1[i], vh1, vl1);
            *reinterpret_cast<unsigned*>(&vth[buf][4 * tx + i][2 * tyq]) = pack2(vh0, vh1);
            *reinterpret_cast<unsigned*>(&vtl[buf][4 * tx + i][2 * tyq]) = pack2(vl0, vl1);
        }
    };

    f32x4 acc[4], aks;
    #pragma unroll
    for (int ms = 0; ms < 4; ++ms) acc[ms] = (f32x4){0.f, 0.f, 0.f, 0.f};
    aks = (f32x4){0.f, 0.f, 0.f, 0.f};
    const bf16x8 ones = ones_frag();

    const int fcol = 8 * (lane >> 4);
    const int frow = lane & 15;

    auto compute = [&](int buf) {
        union { bf16x8 v; uint2 u[2]; } fah, fal;
        {
            const uint2* ph = reinterpret_cast<const uint2*>(&kth[buf][16 * w + frow][fcol]);
            fah.u[0] = ph[0]; fah.u[1] = ph[1];
            const uint2* pl = reinterpret_cast<const uint2*>(&ktl[buf][16 * w + frow][fcol]);
            fal.u[0] = pl[0]; fal.u[1] = pl[1];
        }
        aks = __builtin_amdgcn_mfma_f32_16x16x32_bf16(fah.v, ones, aks, 0, 0, 0);
        aks = __builtin_amdgcn_mfma_f32_16x16x32_bf16(fal.v, ones, aks, 0, 0, 0);
        #pragma unroll
        for (int ms = 0; ms < 4; ++ms) {
            union { bf16x8 v; uint2 u[2]; } fbh, fbl;
            const uint2* ph = reinterpret_cast<const uint2*>(&vth[buf][16 * ms + frow][fcol]);
            fbh.u[0] = ph[0]; fbh.u[1] = ph[1];
            const uint2* pl = reinterpret_cast<const uint2*>(&vtl[buf][16 * ms + frow][fcol]);
            fbl.u[0] = pl[0]; fbl.u[1] = pl[1];
            acc[ms] = __builtin_amdgcn_mfma_f32_16x16x32_bf16(fah.v, fbh.v, acc[ms], 0, 0, 0);
            acc[ms] = __builtin_amdgcn_mfma_f32_16x16x32_bf16(fah.v, fbl.v, acc[ms], 0, 0, 0);
            acc[ms] = __builtin_amdgcn_mfma_f32_16x16x32_bf16(fal.v, fbh.v, acc[ms], 0, 0, 0);
        }
    };

    // prologue: loads for tiles 0(A),1(B),2(A); tile0 staged into buf0
    loadA_A(0);
    loadA_B(1);
    stage(0, kA0, kA1, vA0, vA1, mA);
    loadA_A(2);
    __syncthreads();

    // steady state: one barrier per tile; stage consumes loads issued ~2 tiles ago
    for (int it = 0; it < NT; it += 2) {
        compute(0);                                        // tile it
        stage(1, kB0, kB1, vB0, vB1, mB);                  // tile it+1 -> buf1
        if (it + 3 < NT) loadA_B(it + 3);
        __syncthreads();

        compute(1);                                        // tile it+1
        if (it + 2 < NT) stage(0, kA0, kA1, vA0, vA1, mA); // tile it+2 -> buf0
        if (it + 4 < NT) loadA_A(it + 4);
        __syncthreads();
    }

    float* outp = ws + (size_t)(g * NSPL + sp) * PARTIAL;
    #pragma unroll
    for (int ms = 0; ms < 4; ++ms)
        #pragma unroll
        for (int r = 0; r < 4; ++r)
            outp[(16 * w + 4 * (lane >> 4) + r) * Mc + 16 * ms + frow] = acc[ms][r];

    // ksum: every column of aks holds ksum[row]; lanes with frow==0 write it
    if (frow == 0) {
        #pragma unroll
        for (int r = 0; r < 4; ++r)
            outp[Dc * Mc + 16 * w + 4 * (lane >> 4) + r] = aks[r];
    }
}

// ---------------- Kernel 2: output via split-bf16 MFMA ----------------
template<int NSPL>
__global__ void __launch_bounds__(256, 4)
la_out_mfma(const float* __restrict__ Qg, const float* __restrict__ ws,
            float* __restrict__ Og)
{
    __shared__ unsigned short kvh[Mc][PADD];  // KV hi [m][d]
    __shared__ unsigned short kvl[Mc][PADD];  // KV lo
    __shared__ unsigned short ksh[64];        // ksum hi
    __shared__ unsigned short ksl[64];        // ksum lo
    __shared__ unsigned short qhh[64][PADD];  // phiQ hi [l][d]
    __shared__ unsigned short qll[64][PADD];  // phiQ lo  (total ~35 KB)

    const int t    = threadIdx.x;
    const int tx   = t & 15;
    const int tyq  = t >> 4;
    const int lane = t & 63;
    const int w    = t >> 6;
    const int g    = blockIdx.y;
    const int ls   = blockIdx.x;
    const int h    = g & 7;
    const int bn   = g >> 3;

    const size_t rowbase = (size_t)bn * Lc * HD + (size_t)h * Dc;
    const float* pw = ws + (size_t)g * NSPL * PARTIAL;
    const int lbase = ls * LROWS;

    float4 qr[4];
    auto loadB = [&](int it) {
        const int l0 = lbase + it * 64 + 4 * tyq;
        #pragma unroll
        for (int j = 0; j < 4; ++j)
            qr[j] = *reinterpret_cast<const float4*>(Qg + rowbase + (size_t)(l0 + j) * HD + 4 * tx);
    };
    auto storeB = [&]() {
        #pragma unroll
        for (int j = 0; j < 4; ++j) {
            const int r = 4 * tyq + j;
            const float q[4] = {qr[j].x, qr[j].y, qr[j].z, qr[j].w};
            unsigned short h0, l0, h1, l1, h2, l2, h3, l3;
            splitbf(elup1(q[0]), h0, l0);
            splitbf(elup1(q[1]), h1, l1);
            splitbf(elup1(q[2]), h2, l2);
            splitbf(elup1(q[3]), h3, l3);
            uint2 ph, pl;
            ph.x = pack2(h0, h1); ph.y = pack2(h2, h3);
            pl.x = pack2(l0, l1); pl.y = pack2(l2, l3);
            *reinterpret_cast<uint2*>(&qhh[r][4 * tx]) = ph;
            *reinterpret_cast<uint2*>(&qll[r][4 * tx]) = pl;
        }
    };

    loadB(0);
    // sum the NSPL partials; split into hi/lo, transpose into [m][d]
    #pragma unroll
    for (int e = 0; e < 16; ++e) {
        const int idx = t + 256 * e;
        float s = 0.f;
        #pragma unroll
        for (int sp = 0; sp < NSPL; ++sp) s += pw[sp * PARTIAL + idx];
        unsigned short hh, ll;
        splitbf(s, hh, ll);
        kvh[idx & 63][idx >> 6] = hh;
        kvl[idx & 63][idx >> 6] = ll;
    }
    if (t < 64) {
        float s = 0.f;
        #pragma unroll
        for (int sp = 0; sp < NSPL; ++sp) s += pw[sp * PARTIAL + Dc * Mc + t];
        unsigned short hh, ll;
        splitbf(s, hh, ll);
        ksh[t] = hh;
        ksl[t] = ll;
    }
    storeB();
    __syncthreads();

    const int fcol = 8 * (lane >> 4);
    const int frow = lane & 15;
    const size_t obase = (size_t)bn * Lc * HD + (size_t)h * Mc;

    for (int it = 0; it < NTL; ++it) {
        if (it + 1 < NTL) loadB(it + 1);
        // A-operand fragments (Q hi/lo, two k-halves)
        union { bf16x8 v; uint2 u[2]; } fah0, fal0, fah1, fal1;
        {
            const uint2* p;
            p = reinterpret_cast<const uint2*>(&qhh[16 * w + frow][fcol]);      fah0.u[0] = p[0]; fah0.u[1] = p[1];
            p = reinterpret_cast<const uint2*>(&qll[16 * w + frow][fcol]);      fal0.u[0] = p[0]; fal0.u[1] = p[1];
            p = reinterpret_cast<const uint2*>(&qhh[16 * w + frow][32 + fcol]); fah1.u[0] = p[0]; fah1.u[1] = p[1];
            p = reinterpret_cast<const uint2*>(&qll[16 * w + frow][32 + fcol]); fal1.u[0] = p[0]; fal1.u[1] = p[1];
        }
        f32x4 acc[4], accz;
        #pragma unroll
        for (int ms = 0; ms < 4; ++ms) acc[ms] = (f32x4){0.f, 0.f, 0.f, 0.f};
        accz = (f32x4){0.f, 0.f, 0.f, 0.f};

        #pragma unroll
        for (int ks = 0; ks < 2; ++ks) {
            const bf16x8 fh = ks ? fah1.v : fah0.v;
            const bf16x8 fl = ks ? fal1.v : fal0.v;
            #pragma unroll
            for (int ms = 0; ms < 4; ++ms) {
                union { bf16x8 v; uint2 u[2]; } fbh, fbl;
                const uint2* ph = reinterpret_cast<const uint2*>(&kvh[16 * ms + frow][32 * ks + fcol]);
                fbh.u[0] = ph[0]; fbh.u[1] = ph[1];
                const uint2* pl = reinterpret_cast<const uint2*>(&kvl[16 * ms + frow][32 * ks + fcol]);
                fbl.u[0] = pl[0]; fbl.u[1] = pl[1];
                acc[ms] = __builtin_amdgcn_mfma_f32_16x16x32_bf16(fh, fbh.v, acc[ms], 0, 0, 0);
                acc[ms] = __builtin_amdgcn_mfma_f32_16x16x32_bf16(fh, fbl.v, acc[ms], 0, 0, 0);
                acc[ms] = __builtin_amdgcn_mfma_f32_16x16x32_bf16(fl, fbh.v, acc[ms], 0, 0, 0);
            }
            union { bf16x8 v; uint2 u[2]; } fzh, fzl;
            const uint2* ph = reinterpret_cast<const uint2*>(&ksh[32 * ks + fcol]);
            fzh.u[0] = ph[0]; fzh.u[1] = ph[1];
            const uint2* pl = reinterpret_cast<const uint2*>(&ksl[32 * ks + fcol]);
            fzl.u[0] = pl[0]; fzl.u[1] = pl[1];
            accz = __builtin_amdgcn_mfma_f32_16x16x32_bf16(fh, fzh.v, accz, 0, 0, 0);
            accz = __builtin_amdgcn_mfma_f32_16x16x32_bf16(fh, fzl.v, accz, 0, 0, 0);
            accz = __builtin_amdgcn_mfma_f32_16x16x32_bf16(fl, fzh.v, accz, 0, 0, 0);
        }

        const int lt = lbase + it * 64 + 16 * w + 4 * (lane >> 4);
        #pragma unroll
        for (int r = 0; r < 4; ++r) {
            const float z = 1.0f / (accz[r] + EPSF);
            const size_t ro = obase + (size_t)(lt + r) * HD + frow;
            #pragma unroll
            for (int ms = 0; ms < 4; ++ms)
                Og[ro + 16 * ms] = acc[ms][r] * z;
        }
        __syncthreads();
        if (it + 1 < NTL) storeB();
        __syncthreads();
    }
}

// ---------------- Fallback: fp32 fused kernel (verified R1) ----------------
__global__ void __launch_bounds__(256, 1)
la_fused_kernel(const float* __restrict__ Qg, const float* __restrict__ Kg,
                const float* __restrict__ Vg, const float* __restrict__ Mg,
                float* __restrict__ Og)
{
    __shared__ float lk[32][Dc];
    __shared__ float lv[32][Mc];
    __shared__ float kvt[Dc][Mc];
    __shared__ float ksm[Dc];
    __shared__ float qt[Dc][64];

    const int t  = threadIdx.x;
    const int tx = t & 15;
    const int ty = t >> 4;
    const int g  = blockIdx.x;
    const int h  = g & 7;
    const int bn = g >> 3;
    const int b  = g >> 6;

    const size_t rowbase = (size_t)bn * Sc * HD + (size_t)h * Dc;
    const size_t mbase   = (size_t)b * Sc;

    const int d0 = tx * 4, m0 = ty * 4, c4 = tx * 4, r0 = ty;

    float acc[4][4] = {{0.f,0.f,0.f,0.f},{0.f,0.f,0.f,0.f},{0.f,0.f,0.f,0.f},{0.f,0.f,0.f,0.f}};
    float ks[4] = {0.f, 0.f, 0.f, 0.f};
    float4 kr[2], vr[2];
    float  mr[2];

    auto loadA = [&](int it) {
        const int s0 = it * 32;
        #pragma unroll
        for (int k = 0; k < 2; ++k) {
            const int r = r0 + 16 * k;
            const size_t off = rowbase + (size_t)(s0 + r) * HD + c4;
            kr[k] = *reinterpret_cast<const float4*>(Kg + off);
            vr[k] = *reinterpret_cast<const float4*>(Vg + off);
            mr[k] = Mg[mbase + s0 + r];
        }
    };
    auto storeA = [&]() {
        #pragma unroll
        for (int k = 0; k < 2; ++k) {
            const int r = r0 + 16 * k;
            float4 kk;
            kk.x = elup1(kr[k].x) * mr[k];
            kk.y = elup1(kr[k].y) * mr[k];
            kk.z = elup1(kr[k].z) * mr[k];
            kk.w = elup1(kr[k].w) * mr[k];
            *reinterpret_cast<float4*>(&lk[r][c4]) = kk;
            *reinterpret_cast<float4*>(&lv[r][c4]) = vr[k];
        }
    };

    loadA(0);
    storeA();
    __syncthreads();
    for (int it = 0; it < Sc / 32; ++it) {
        if (it + 1 < Sc / 32) loadA(it + 1);
        #pragma unroll 8
        for (int r = 0; r < 32; ++r) {
            const float4 k4 = *reinterpret_cast<const float4*>(&lk[r][d0]);
            const float4 v4 = *reinterpret_cast<const float4*>(&lv[r][m0]);
            const float kk[4] = {k4.x, k4.y, k4.z, k4.w};
            const float vv[4] = {v4.x, v4.y, v4.z, v4.w};
            ks[0] += kk[0]; ks[1] += kk[1]; ks[2] += kk[2]; ks[3] += kk[3];
            #pragma unroll
            for (int i = 0; i < 4; ++i)
                #pragma unroll
                for (int j = 0; j < 4; ++j)
                    acc[i][j] += kk[i] * vv[j];
        }
        __syncthreads();
        if (it + 1 < Sc / 32) storeA();
        __syncthreads();
    }

    #pragma unroll
    for (int i = 0; i < 4; ++i) {
        float4 w;
        w.x = acc[i][0]; w.y = acc[i][1]; w.z = acc[i][2]; w.w = acc[i][3];
        *reinterpret_cast<float4*>(&kvt[d0 + i][m0]) = w;
    }
    if (ty == 0) {
        #pragma unroll
        for (int i = 0; i < 4; ++i) ksm[d0 + i] = ks[i];
    }
    __syncthreads();

    float4 qr[4];
    auto loadB = [&](int it) {
        const int l0 = it * 64;
        #pragma unroll
        for (int k = 0; k < 4; ++k) {
            const int r = r0 + 16 * k;
            const size_t off = rowbase + (size_t)(l0 + r) * HD + c4;
            qr[k] = *reinterpret_cast<const float4*>(Qg + off);
        }
    };
    const int swzw = (tx & 7) << 2;
    auto storeB = [&]() {
        #pragma unroll
        for (int k = 0; k < 4; ++k) {
            const int r = r0 + 16 * k;
            const int lidx = r ^ swzw;
            qt[c4 + 0][lidx] = elup1(qr[k].x);
            qt[c4 + 1][lidx] = elup1(qr[k].y);
            qt[c4 + 2][lidx] = elup1(qr[k].z);
            qt[c4 + 3][lidx] = elup1(qr[k].w);
        }
    };

    loadB(0);
    storeB();
    __syncthreads();
    for (int it = 0; it < Lc / 64; ++it) {
        if (it + 1 < Lc / 64) loadB(it + 1);
        float accB[4][4] = {{0.f,0.f,0.f,0.f},{0.f,0.f,0.f,0.f},{0.f,0.f,0.f,0.f},{0.f,0.f,0.f,0.f}};
        float za[4] = {0.f, 0.f, 0.f, 0.f};
        #pragma unroll 8
        for (int d = 0; d < Dc; ++d) {
            const int swz = ((d >> 2) & 7) << 2;
            const float4 q4  = *reinterpret_cast<const float4*>(&qt[d][(4 * ty) ^ swz]);
            const float4 kv4 = *reinterpret_cast<const float4*>(&kvt[d][4 * tx]);
            const float kd = ksm[d];
            const float qq[4] = {q4.x, q4.y, q4.z, q4.w};
            const float kv[4] = {kv4.x, kv4.y, kv4.z, kv4.w};
            #pragma unroll
            for (int i = 0; i < 4; ++i) {
                za[i] += qq[i] * kd;
                #pragma unroll
                for (int j = 0; j < 4; ++j)
                    accB[i][j] += qq[i] * kv[j];
            }
        }
        const int l0 = it * 64;
        const size_t obase = (size_t)bn * Lc * HD + (size_t)h * Mc;
        #pragma unroll
        for (int i = 0; i < 4; ++i) {
            const int l = l0 + 4 * ty + i;
            const float z = 1.0f / (za[i] + EPSF);
            float4 o;
            o.x = accB[i][0] * z; o.y = accB[i][1] * z;
            o.z = accB[i][2] * z; o.w = accB[i][3] * z;
            *reinterpret_cast<float4*>(Og + obase + (size_t)l * HD + 4 * tx) = o;
        }
        __syncthreads();
        if (it + 1 < Lc / 64) storeB();
        __syncthreads();
    }
}

extern "C" void kernel_launch(void* const* d_in, const int* in_sizes, int n_in,
                              void* d_out, int out_size, void* d_ws, size_t ws_size,
                              hipStream_t stream) {
    const float* Qg = (const float*)d_in[0];
    const float* Kg = (const float*)d_in[1];
    const float* Vg = (const float*)d_in[2];
    const float* Mg = (const float*)d_in[3];
    float* Og = (float*)d_out;

    const size_t need4 = (size_t)GROUPS * 4 * PARTIAL * sizeof(float);
    if (ws_size >= need4) {
        float* ws = (float*)d_ws;
        hipLaunchKernelGGL((la_kv_mfma<4>), dim3(4, GROUPS), dim3(256), 0, stream,
                           Kg, Vg, Mg, ws);
        hipLaunchKernelGGL((la_out_mfma<4>), dim3(LSPLITS, GROUPS), dim3(256), 0, stream,
                           Qg, ws, Og);
    } else {
        hipLaunchKernelGGL(la_fused_kernel, dim3(GROUPS), dim3(256), 0, stream,
                           Qg, Kg, Vg, Mg, Og);
    }
}